// Round 1
// baseline (3274.545 us; speedup 1.0000x reference)
//
#include <hip/hip_runtime.h>
#include <math.h>

#define N_SEQ 4096
#define D_MODEL 1024

// ---------------------------------------------------------------------------
// GEMM: C[M,N] = A[M,K] * B[K,N], fp32 row-major. 64x64 block tile, BK=16,
// 256 threads, 4x4 register tile per thread, float4 LDS reads.
// ---------------------------------------------------------------------------
#define GBM 64
#define GBN 64
#define GBK 16

__global__ __launch_bounds__(256)
void gemm_f32(const float* __restrict__ A, const float* __restrict__ B,
              float* __restrict__ C, int M, int Nn, int K) {
  __shared__ float As[GBK][68];   // stride 68: float4-aligned, banks spread
  __shared__ float Bs[GBK][64];
  const int tid = threadIdx.x;
  const int tx = tid & 15, ty = tid >> 4;
  const int m0 = blockIdx.y * GBM, n0 = blockIdx.x * GBN;
  float acc[4][4] = {};

  for (int k0 = 0; k0 < K; k0 += GBK) {
    // A tile: 64 rows x 16 k — one float4 per thread, transposed into As[k][m]
    {
      const int r = tid >> 2, c4 = tid & 3;
      const float4 v = *(const float4*)&A[(size_t)(m0 + r) * K + k0 + c4 * 4];
      As[c4 * 4 + 0][r] = v.x;
      As[c4 * 4 + 1][r] = v.y;
      As[c4 * 4 + 2][r] = v.z;
      As[c4 * 4 + 3][r] = v.w;
    }
    // B tile: 16 k x 64 n — one float4 per thread, coalesced
    {
      const int r = tid >> 4, c4 = tid & 15;
      *(float4*)&Bs[r][c4 * 4] =
          *(const float4*)&B[(size_t)(k0 + r) * Nn + n0 + c4 * 4];
    }
    __syncthreads();
#pragma unroll
    for (int k = 0; k < GBK; ++k) {
      const float4 a4 = *(const float4*)&As[k][ty * 4];
      const float4 b4 = *(const float4*)&Bs[k][tx * 4];
      const float a[4] = {a4.x, a4.y, a4.z, a4.w};
      const float b[4] = {b4.x, b4.y, b4.z, b4.w};
#pragma unroll
      for (int i = 0; i < 4; ++i)
#pragma unroll
        for (int j = 0; j < 4; ++j) acc[i][j] += a[i] * b[j];
    }
    __syncthreads();
  }
#pragma unroll
  for (int i = 0; i < 4; ++i) {
    float4 v = make_float4(acc[i][0], acc[i][1], acc[i][2], acc[i][3]);
    *(float4*)&C[(size_t)(m0 + ty * 4 + i) * Nn + n0 + tx * 4] = v;
  }
}

// ---------------------------------------------------------------------------
// Flash-style causal attention, fp32.
//   o[i,:] = softmax_j<=i( q[i]·x[j] ) @ x
// BQ=8 query rows per block, 128 threads (r = tid>>4 in 0..7, cs = tid&15).
// Key tiles of 64; D=1024 streamed through LDS in 128-wide chunks.
// Each block processes q-tile pair (b, 511-b) for causal load balance.
// ---------------------------------------------------------------------------
#define BQ 8
#define BKV 64
#define DC 128
#define XSS 132   // Xs/Qs LDS stride: %32==4 -> 2-way (free) bank pattern

__global__ __launch_bounds__(128)
void attn_flash(const float* __restrict__ q, const float* __restrict__ x,
                float* __restrict__ o) {
  __shared__ float Qs[BQ][XSS];
  __shared__ float Xs[BKV][XSS];
  __shared__ float Sp[BQ][BKV];
  __shared__ float red[BQ][16];
  __shared__ float mrow[BQ], lrow[BQ], arow[BQ];

  const int tid = threadIdx.x;
  const int r = tid >> 4;   // query row within tile (0..7)
  const int cs = tid & 15;  // key-segment (QK) / d-segment (PV)

  for (int half = 0; half < 2; ++half) {
    const int tile = (half == 0) ? (int)blockIdx.x
                                 : (2 * (int)gridDim.x - 1 - (int)blockIdx.x);
    const int q0 = tile * BQ;
    const int qi = q0 + r;

    float O[64];
#pragma unroll
    for (int i = 0; i < 64; ++i) O[i] = 0.f;
    if (tid < BQ) { mrow[tid] = -INFINITY; lrow[tid] = 0.f; }
    __syncthreads();

    const int nkt = q0 / 64 + 1;  // key tiles needed (causal)
    for (int kt = 0; kt < nkt; ++kt) {
      const int key0 = kt * BKV;

      // ---- QK^T: sacc[j4] = q[qi] · x[key0 + cs + j4*16] ----
      float sacc[4] = {0.f, 0.f, 0.f, 0.f};
      for (int c = 0; c < 8; ++c) {
#pragma unroll
        for (int i = 0; i < 2; ++i) {  // Qs: 8x128
          const int l2 = tid + i * 128;
          const int rr = l2 >> 5, c4 = l2 & 31;
          *(float4*)&Qs[rr][c4 * 4] =
              *(const float4*)&q[(size_t)(q0 + rr) * D_MODEL + c * DC + c4 * 4];
        }
#pragma unroll
        for (int i = 0; i < 16; ++i) {  // Xs: 64x128
          const int l2 = tid + i * 128;
          const int rr = l2 >> 5, c4 = l2 & 31;
          *(float4*)&Xs[rr][c4 * 4] =
              *(const float4*)&x[(size_t)(key0 + rr) * D_MODEL + c * DC + c4 * 4];
        }
        __syncthreads();
#pragma unroll 8
        for (int kk = 0; kk < DC; kk += 4) {
          const float4 q4 = *(const float4*)&Qs[r][kk];
#pragma unroll
          for (int j4 = 0; j4 < 4; ++j4) {
            const float4 x4 = *(const float4*)&Xs[cs + j4 * 16][kk];
            sacc[j4] += q4.x * x4.x + q4.y * x4.y + q4.z * x4.z + q4.w * x4.w;
          }
        }
        __syncthreads();
      }

      // ---- online softmax update ----
      bool valid[4];
      float tmax = -INFINITY;
#pragma unroll
      for (int j4 = 0; j4 < 4; ++j4) {
        valid[j4] = (key0 + cs + j4 * 16) <= qi;
        if (valid[j4]) tmax = fmaxf(tmax, sacc[j4]);
      }
      red[r][cs] = tmax;
      __syncthreads();
      if (tid < BQ) {
        const float mold = mrow[tid];
        float mt = mold;
#pragma unroll
        for (int i = 0; i < 16; ++i) mt = fmaxf(mt, red[tid][i]);
        arow[tid] = expf(mold - mt);  // exp(-inf)=0 on first tile
        mrow[tid] = mt;
      }
      __syncthreads();
      const float mnew = mrow[r];
      float psum = 0.f;
#pragma unroll
      for (int j4 = 0; j4 < 4; ++j4) {
        const float p = valid[j4] ? expf(sacc[j4] - mnew) : 0.f;
        Sp[r][cs + j4 * 16] = p;
        psum += p;
      }
      red[r][cs] = psum;
      __syncthreads();
      if (tid < BQ) {
        float s = 0.f;
#pragma unroll
        for (int i = 0; i < 16; ++i) s += red[tid][i];
        lrow[tid] = lrow[tid] * arow[tid] + s;
      }
      __syncthreads();

      const float alpha = arow[r];
#pragma unroll
      for (int i = 0; i < 64; ++i) O[i] *= alpha;

      // ---- PV: O[r, :] += Sp[r, :] @ x[key0:key0+64, :] ----
      for (int c = 0; c < 8; ++c) {
#pragma unroll
        for (int i = 0; i < 16; ++i) {
          const int l2 = tid + i * 128;
          const int rr = l2 >> 5, c4 = l2 & 31;
          *(float4*)&Xs[rr][c4 * 4] =
              *(const float4*)&x[(size_t)(key0 + rr) * D_MODEL + c * DC + c4 * 4];
        }
        __syncthreads();
#pragma unroll 4
        for (int j = 0; j < BKV; ++j) {
          const float p = Sp[r][j];
          const float4 xa = *(const float4*)&Xs[j][cs * 4];
          const float4 xb = *(const float4*)&Xs[j][64 + cs * 4];
          O[c * 8 + 0] += p * xa.x; O[c * 8 + 1] += p * xa.y;
          O[c * 8 + 2] += p * xa.z; O[c * 8 + 3] += p * xa.w;
          O[c * 8 + 4] += p * xb.x; O[c * 8 + 5] += p * xb.y;
          O[c * 8 + 6] += p * xb.z; O[c * 8 + 7] += p * xb.w;
        }
        __syncthreads();
      }
    }

    // ---- epilogue: normalize and store ----
    const float inv_l = 1.f / lrow[r];
#pragma unroll
    for (int c = 0; c < 8; ++c) {
      const float4 va = make_float4(O[c * 8 + 0] * inv_l, O[c * 8 + 1] * inv_l,
                                    O[c * 8 + 2] * inv_l, O[c * 8 + 3] * inv_l);
      const float4 vb = make_float4(O[c * 8 + 4] * inv_l, O[c * 8 + 5] * inv_l,
                                    O[c * 8 + 6] * inv_l, O[c * 8 + 7] * inv_l);
      *(float4*)&o[(size_t)qi * D_MODEL + c * DC + cs * 4] = va;
      *(float4*)&o[(size_t)qi * D_MODEL + c * DC + 64 + cs * 4] = vb;
    }
    __syncthreads();  // smem reused by next half
  }
}

// ---------------------------------------------------------------------------
extern "C" void kernel_launch(void* const* d_in, const int* in_sizes, int n_in,
                              void* d_out, int out_size, void* d_ws,
                              size_t ws_size, hipStream_t stream) {
  (void)in_sizes; (void)n_in; (void)out_size; (void)ws_size;
  const float* x   = (const float*)d_in[0];
  const float* wqk = (const float*)d_in[1];
  const float* wov = (const float*)d_in[2];
  float* out = (float*)d_out;

  // workspace: q (16 MB) | o (16 MB)
  float* q_ws = (float*)d_ws;
  float* o_ws = q_ws + (size_t)N_SEQ * D_MODEL;

  // q = x @ wqk
  gemm_f32<<<dim3(D_MODEL / GBN, N_SEQ / GBM), 256, 0, stream>>>(
      x, wqk, q_ws, N_SEQ, D_MODEL, D_MODEL);
  // o = softmax(tril(q x^T)) x   (flash, causal, load-balanced pairs)
  attn_flash<<<256, 128, 0, stream>>>(q_ws, x, o_ws);
  // out = o @ wov
  gemm_f32<<<dim3(D_MODEL / GBN, N_SEQ / GBM), 256, 0, stream>>>(
      o_ws, wov, out, N_SEQ, D_MODEL, D_MODEL);
}

// Round 2
// 1202.251 us; speedup vs baseline: 2.7237x; 2.7237x over previous
//
#include <hip/hip_runtime.h>
#include <hip/hip_bf16.h>
#include <math.h>

#define N_SEQ 4096
#define D_MODEL 1024
#define BAND 512
#define NBAND (N_SEQ / BAND)

typedef __attribute__((ext_vector_type(8))) short short8;
typedef __attribute__((ext_vector_type(4))) float f32x4;

__device__ inline short f2bf(float f) {
  __hip_bfloat16 h = __float2bfloat16(f);
  return *reinterpret_cast<short*>(&h);
}

// ---------------------------------------------------------------------------
// GEMM: C[M,N] = A[M,K] * B[K,N], fp32 row-major. 64x64 tile, BK=16, 256 thr.
// ---------------------------------------------------------------------------
__global__ __launch_bounds__(256)
void gemm_f32(const float* __restrict__ A, const float* __restrict__ B,
              float* __restrict__ C, int M, int Nn, int K) {
  __shared__ float As[16][68];
  __shared__ float Bs[16][68];
  const int tid = threadIdx.x;
  const int tx = tid & 15, ty = tid >> 4;
  const int m0 = blockIdx.y * 64, n0 = blockIdx.x * 64;
  float acc[4][4] = {};
  for (int k0 = 0; k0 < K; k0 += 16) {
    {
      const int r = tid >> 2, c4 = (tid & 3) * 4;
      const float4 v = *(const float4*)&A[(size_t)(m0 + r) * K + k0 + c4];
      As[c4 + 0][r] = v.x; As[c4 + 1][r] = v.y;
      As[c4 + 2][r] = v.z; As[c4 + 3][r] = v.w;
    }
    {
      const int r = tid >> 4, c4 = (tid & 15) * 4;
      *(float4*)&Bs[r][c4] = *(const float4*)&B[(size_t)(k0 + r) * Nn + n0 + c4];
    }
    __syncthreads();
#pragma unroll
    for (int k = 0; k < 16; ++k) {
      const float4 a4 = *(const float4*)&As[k][ty * 4];
      const float4 b4 = *(const float4*)&Bs[k][tx * 4];
      const float a[4] = {a4.x, a4.y, a4.z, a4.w};
      const float b[4] = {b4.x, b4.y, b4.z, b4.w};
#pragma unroll
      for (int i = 0; i < 4; ++i)
#pragma unroll
        for (int j = 0; j < 4; ++j) acc[i][j] += a[i] * b[j];
    }
    __syncthreads();
  }
#pragma unroll
  for (int i = 0; i < 4; ++i) {
    float4 v = make_float4(acc[i][0], acc[i][1], acc[i][2], acc[i][3]);
    *(float4*)&C[(size_t)(m0 + ty * 4 + i) * Nn + n0 + tx * 4] = v;
  }
}

// ---------------------------------------------------------------------------
// out[c][r] = bf16(in[r][c]); in: R x C fp32. 64x64 tiles via LDS.
// ---------------------------------------------------------------------------
__global__ __launch_bounds__(256)
void transpose_bf16(const float* __restrict__ in, short* __restrict__ out,
                    int R, int C) {
  __shared__ short T[64][72];
  const int tid = threadIdx.x;
  const int r0 = blockIdx.x * 64, c0 = blockIdx.y * 64;
#pragma unroll
  for (int i = 0; i < 4; ++i) {
    const int rr = (tid >> 4) + i * 16;
    const int cc = (tid & 15) * 4;
    const float4 v = *(const float4*)&in[(size_t)(r0 + rr) * C + c0 + cc];
    T[rr][cc + 0] = f2bf(v.x); T[rr][cc + 1] = f2bf(v.y);
    T[rr][cc + 2] = f2bf(v.z); T[rr][cc + 3] = f2bf(v.w);
  }
  __syncthreads();
#pragma unroll
  for (int i = 0; i < 2; ++i) {
    const int idx = tid + i * 256;
    const int oc = idx >> 3;        // column of `in` == row of `out`
    const int ch = (idx & 7) * 8;   // 8-elem chunk along r
    float4 u;
    short* tmp = (short*)&u;
#pragma unroll
    for (int j = 0; j < 8; ++j) tmp[j] = T[ch + j][oc];
    *(float4*)&out[(size_t)(c0 + oc) * R + r0 + ch] = u;
  }
}

// ---------------------------------------------------------------------------
// QK^T band: S_band[lr*64+i][j] = q[gm0+i] . x[n0+j], fp32. Causal tiles only.
// Grid: flat over (lr, kt) with kt <= base_rowtile+lr. Same shape as gemm_f32.
// ---------------------------------------------------------------------------
__global__ __launch_bounds__(256)
void qk_band(const float* __restrict__ q, const float* __restrict__ x,
             float* __restrict__ S, int base_rowtile) {
  int idx = blockIdx.x;
  int lr = 0;
#pragma unroll
  for (int t = 0; t < 8; ++t) {
    const int cnt = base_rowtile + t + 1;
    if (idx < cnt) { lr = t; break; }
    idx -= cnt;
  }
  const int kt = idx;
  const int gm0 = (base_rowtile + lr) * 64;  // global q row base
  const int n0 = kt * 64;                    // global key base
  __shared__ float As[16][68];
  __shared__ float Bs[16][68];
  const int tid = threadIdx.x;
  const int tx = tid & 15, ty = tid >> 4;
  float acc[4][4] = {};
  for (int k0 = 0; k0 < D_MODEL; k0 += 16) {
    const int r = tid >> 2, c4 = (tid & 3) * 4;
    const float4 a = *(const float4*)&q[(size_t)(gm0 + r) * D_MODEL + k0 + c4];
    const float4 b = *(const float4*)&x[(size_t)(n0 + r) * D_MODEL + k0 + c4];
    As[c4 + 0][r] = a.x; As[c4 + 1][r] = a.y;
    As[c4 + 2][r] = a.z; As[c4 + 3][r] = a.w;
    Bs[c4 + 0][r] = b.x; Bs[c4 + 1][r] = b.y;
    Bs[c4 + 2][r] = b.z; Bs[c4 + 3][r] = b.w;
    __syncthreads();
#pragma unroll
    for (int k = 0; k < 16; ++k) {
      const float4 a4 = *(const float4*)&As[k][ty * 4];
      const float4 b4 = *(const float4*)&Bs[k][tx * 4];
      const float aa[4] = {a4.x, a4.y, a4.z, a4.w};
      const float bb[4] = {b4.x, b4.y, b4.z, b4.w};
#pragma unroll
      for (int i = 0; i < 4; ++i)
#pragma unroll
        for (int j = 0; j < 4; ++j) acc[i][j] += aa[i] * bb[j];
    }
    __syncthreads();
  }
  const int sr0 = lr * 64;  // band-local row
#pragma unroll
  for (int i = 0; i < 4; ++i) {
    float4 v = make_float4(acc[i][0], acc[i][1], acc[i][2], acc[i][3]);
    *(float4*)&S[(size_t)(sr0 + ty * 4 + i) * N_SEQ + n0 + tx * 4] = v;
  }
}

// ---------------------------------------------------------------------------
// Row softmax: P[li][j] = exp(S[li][j]-m)/l for j<=gi, 0-padded to key-tile
// boundary. One block per row, 256 threads, 3 passes (max, sum, write).
// ---------------------------------------------------------------------------
__global__ __launch_bounds__(256)
void softmax_band(const float* __restrict__ S, short* __restrict__ P,
                  int row0) {
  const int li = blockIdx.x;
  const int gi = row0 + li;
  const int valid = gi + 1;
  const int padded = ((gi >> 6) + 1) << 6;
  const float* srow = S + (size_t)li * N_SEQ;
  short* prow = P + (size_t)li * N_SEQ;
  const int tid = threadIdx.x;
  const int w = tid >> 6, lane = tid & 63;
  __shared__ float wred[4];
  __shared__ float sm, sil;

  float m = -1e30f;
  for (int j = tid; j < valid; j += 256) m = fmaxf(m, srow[j]);
#pragma unroll
  for (int off = 32; off > 0; off >>= 1) m = fmaxf(m, __shfl_down(m, off));
  if (lane == 0) wred[w] = m;
  __syncthreads();
  if (tid == 0)
    sm = fmaxf(fmaxf(wred[0], wred[1]), fmaxf(wred[2], wred[3]));
  __syncthreads();
  m = sm;

  float l = 0.f;
  for (int j = tid; j < valid; j += 256) l += __expf(srow[j] - m);
#pragma unroll
  for (int off = 32; off > 0; off >>= 1) l += __shfl_down(l, off);
  if (lane == 0) wred[w] = l;
  __syncthreads();
  if (tid == 0) sil = 1.f / (wred[0] + wred[1] + wred[2] + wred[3]);
  __syncthreads();
  const float il = sil;

  for (int j = tid; j < padded; j += 256) {
    const float v = (j < valid) ? __expf(srow[j] - m) * il : 0.f;
    prow[j] = f2bf(v);
  }
}

// ---------------------------------------------------------------------------
// bf16 MFMA GEMM: C[m][n] = sum_k A[m][k]*Bt[n][k]. 64x64 tile, 4 waves,
// 16x16x32 MFMA. A rows are block-local (A base pre-offset by caller);
// output rows offset by out_row0. ktiles = ktiles_base + y*ktiles_per_y.
// ---------------------------------------------------------------------------
__global__ __launch_bounds__(256)
void mfma_gemm_nt(const short* __restrict__ A, int lda,
                  const short* __restrict__ Bt, int ldb,
                  void* __restrict__ Cout, int ldc, int out_row0,
                  int ktiles_base, int ktiles_per_y, int out_is_bf16) {
  __shared__ short Am[64][72];
  __shared__ short Bn[64][72];
  const int tid = threadIdx.x;
  const int m0 = blockIdx.y * 64;
  const int n0 = blockIdx.x * 64;
  const int ktiles = ktiles_base + (int)blockIdx.y * ktiles_per_y;
  const int w = tid >> 6, lane = tid & 63;
  const int quad = lane >> 4, l15 = lane & 15;
  f32x4 acc[4];
#pragma unroll
  for (int t = 0; t < 4; ++t)
#pragma unroll
    for (int i = 0; i < 4; ++i) acc[t][i] = 0.f;

  for (int kt = 0; kt < ktiles; ++kt) {
#pragma unroll
    for (int i = 0; i < 2; ++i) {
      const int idx = tid + i * 256;
      const int r = idx >> 3, ch = (idx & 7) * 8;
      *(float4*)&Am[r][ch] =
          *(const float4*)&A[(size_t)(m0 + r) * lda + kt * 64 + ch];
      *(float4*)&Bn[r][ch] =
          *(const float4*)&Bt[(size_t)(n0 + r) * ldb + kt * 64 + ch];
    }
    __syncthreads();
#pragma unroll
    for (int s = 0; s < 2; ++s) {
      const short8 a = *(const short8*)&Am[w * 16 + l15][s * 32 + quad * 8];
#pragma unroll
      for (int t = 0; t < 4; ++t) {
        const short8 b = *(const short8*)&Bn[t * 16 + l15][s * 32 + quad * 8];
        acc[t] = __builtin_amdgcn_mfma_f32_16x16x32_bf16(a, b, acc[t], 0, 0, 0);
      }
    }
    __syncthreads();
  }
#pragma unroll
  for (int t = 0; t < 4; ++t)
#pragma unroll
    for (int r = 0; r < 4; ++r) {
      const int row = out_row0 + m0 + w * 16 + quad * 4 + r;
      const int col = n0 + t * 16 + l15;
      if (out_is_bf16)
        ((short*)Cout)[(size_t)row * ldc + col] = f2bf(acc[t][r]);
      else
        ((float*)Cout)[(size_t)row * ldc + col] = acc[t][r];
    }
}

// ---------------------------------------------------------------------------
extern "C" void kernel_launch(void* const* d_in, const int* in_sizes, int n_in,
                              void* d_out, int out_size, void* d_ws,
                              size_t ws_size, hipStream_t stream) {
  (void)in_sizes; (void)n_in; (void)out_size; (void)ws_size;
  const float* x   = (const float*)d_in[0];
  const float* wqk = (const float*)d_in[1];
  const float* wov = (const float*)d_in[2];
  float* out = (float*)d_out;

  char* w = (char*)d_ws;
  short* xbT  = (short*)(w);                          // 1024x4096 bf16, 8 MB
  short* wovT = (short*)(w + (8ull << 20));           // 1024x1024 bf16, 2 MB
  float* q    = (float*)(w + (10ull << 20));          // 4096x1024 f32, 16 MB
  float* Sb   = (float*)(w + (26ull << 20));          // 512x4096 f32,  8 MB
  short* Pb   = (short*)(w + (34ull << 20));          // 512x4096 bf16, 4 MB
  short* ob   = (short*)(w + (38ull << 20));          // 4096x1024 bf16,8 MB
                                                      // total 46 MB

  // prep: x^T and wov^T in bf16
  transpose_bf16<<<dim3(N_SEQ / 64, D_MODEL / 64), 256, 0, stream>>>(
      x, xbT, N_SEQ, D_MODEL);
  transpose_bf16<<<dim3(D_MODEL / 64, D_MODEL / 64), 256, 0, stream>>>(
      wov, wovT, D_MODEL, D_MODEL);

  // q = x @ wqk (fp32 — precision-critical upstream of softmax)
  gemm_f32<<<dim3(D_MODEL / 64, N_SEQ / 64), 256, 0, stream>>>(
      x, wqk, q, N_SEQ, D_MODEL, D_MODEL);

  for (int b = 0; b < NBAND; ++b) {
    const int base_rt = (b * BAND) / 64;  // 8*b
    const int ntiles = 8 * base_rt + 36;  // sum_{lr<8}(base_rt+lr+1)
    qk_band<<<ntiles, 256, 0, stream>>>(q, x, Sb, base_rt);
    softmax_band<<<BAND, 256, 0, stream>>>(Sb, Pb, b * BAND);
    // o[band] = P_band @ x   (bf16 MFMA; B = x^T so k is contiguous)
    mfma_gemm_nt<<<dim3(D_MODEL / 64, BAND / 64), 256, 0, stream>>>(
        Pb, N_SEQ, xbT, N_SEQ, ob, D_MODEL, b * BAND,
        b * BAND / 64 + 1, 1, 1);
  }

  // out = o @ wov (bf16 MFMA)
  mfma_gemm_nt<<<dim3(D_MODEL / 64, N_SEQ / 64), 256, 0, stream>>>(
      ob, D_MODEL, wovT, D_MODEL, out, D_MODEL, 0, D_MODEL / 64, 0, 0);
}

// Round 3
// 323.184 us; speedup vs baseline: 10.1321x; 3.7200x over previous
//
#include <hip/hip_runtime.h>
#include <hip/hip_bf16.h>
#include <math.h>

#define N_SEQ 4096
#define D_MODEL 1024

typedef __attribute__((ext_vector_type(8))) short short8;
typedef __attribute__((ext_vector_type(4))) float f32x4;

__device__ __forceinline__ short f2bf(float f) {
  __hip_bfloat16 h = __float2bfloat16(f);
  return *reinterpret_cast<short*>(&h);
}
__device__ __forceinline__ float bf2f(short h) {
  return __uint_as_float(((unsigned)(unsigned short)h) << 16);
}

// async global->LDS, 16B per lane. LDS dest must be wave-uniform base + lane*16.
__device__ __forceinline__ void gload16(const short* g, short* l) {
  __builtin_amdgcn_global_load_lds(
      (const __attribute__((address_space(1))) void*)g,
      (__attribute__((address_space(3))) void*)l, 16, 0, 0);
}

template <int BK>
__device__ __forceinline__ void stage_tile(const short* __restrict__ src,
                                           int ld, int r0, int k0,
                                           short* dst, int tid) {
#pragma unroll
  for (int i = 0; i < BK / 16; ++i) {
    const int cid = i * 256 + tid;
    const int row = cid / (BK / 8);
    const int col = (cid % (BK / 8)) * 8;
    gload16(&src[(size_t)(r0 + row) * ld + k0 + col], &dst[cid * 8]);
  }
}

// ---------------------------------------------------------------------------
// 128x128-tile bf16 MFMA GEMM (NT: both A and B have contiguous K rows).
// 256 thr = 4 waves in 2x2; each wave 64x64 via 4x4 grid of 16x16x32 MFMA.
// HAS_LO: 3-product split-bf16 (fp32-accurate): Ah*Bh + Ah*Bl + Al*Bh. BK=32.
// OUT_MODE: 0 = fp32, 1 = bf16, 2 = bf16 hi+lo split.
// CAUSAL: flat blockIdx.x -> (mt, ct<=rt0+mt); else (blockIdx.y, blockIdx.x).
// K = k_base + k_per_mt * (rt0 + mt)   (variable-K for causal PV).
// ---------------------------------------------------------------------------
template <bool HAS_LO, int OUT_MODE, bool CAUSAL>
__global__ __launch_bounds__(256, 2)
void mfma_nt(const short* __restrict__ Ah, const short* __restrict__ Al,
             int lda, const short* __restrict__ Bh,
             const short* __restrict__ Bl, int ldb, void* __restrict__ C0,
             void* __restrict__ C1, int ldc, int out_row0, int rt0,
             int k_base, int k_per_mt) {
  constexpr int BK = HAS_LO ? 32 : 64;
  __shared__ short sA[8192];  // hi [0,4096) + lo [4096,8192) when HAS_LO
  __shared__ short sB[8192];

  int mt, nt;
  if (CAUSAL) {
    int f = blockIdx.x;
    int lrt = 0;
    for (;;) {
      const int cnt = rt0 + lrt + 1;
      if (f < cnt) break;
      f -= cnt;
      ++lrt;
    }
    mt = lrt;
    nt = f;
  } else {
    mt = blockIdx.y;
    nt = blockIdx.x;
  }
  const int m0 = mt * 128, n0 = nt * 128;
  const int K = k_base + k_per_mt * (rt0 + mt);

  const int tid = threadIdx.x;
  const int w = tid >> 6, lane = tid & 63;
  const int quad = lane >> 4, l15 = lane & 15;
  const int wm = (w >> 1) * 64, wn = (w & 1) * 64;

  f32x4 acc[4][4];
#pragma unroll
  for (int mi = 0; mi < 4; ++mi)
#pragma unroll
    for (int ni = 0; ni < 4; ++ni)
#pragma unroll
      for (int r = 0; r < 4; ++r) acc[mi][ni][r] = 0.f;

  const int nk = K / BK;
  for (int kt = 0; kt < nk; ++kt) {
    const int k0 = kt * BK;
    stage_tile<BK>(Ah, lda, m0, k0, sA, tid);
    stage_tile<BK>(Bh, ldb, n0, k0, sB, tid);
    if (HAS_LO) {
      stage_tile<BK>(Al, lda, m0, k0, sA + 4096, tid);
      stage_tile<BK>(Bl, ldb, n0, k0, sB + 4096, tid);
    }
    __syncthreads();
#pragma unroll
    for (int s = 0; s < BK / 32; ++s) {
      short8 a[4], b[4];
#pragma unroll
      for (int mi = 0; mi < 4; ++mi)
        a[mi] = *(const short8*)&sA[(wm + mi * 16 + l15) * BK + s * 32 + quad * 8];
#pragma unroll
      for (int ni = 0; ni < 4; ++ni)
        b[ni] = *(const short8*)&sB[(wn + ni * 16 + l15) * BK + s * 32 + quad * 8];
      if (HAS_LO) {
        short8 al[4], bl[4];
#pragma unroll
        for (int mi = 0; mi < 4; ++mi)
          al[mi] = *(const short8*)&sA[4096 + (wm + mi * 16 + l15) * BK + quad * 8];
#pragma unroll
        for (int ni = 0; ni < 4; ++ni)
          bl[ni] = *(const short8*)&sB[4096 + (wn + ni * 16 + l15) * BK + quad * 8];
#pragma unroll
        for (int mi = 0; mi < 4; ++mi)
#pragma unroll
          for (int ni = 0; ni < 4; ++ni) {
            acc[mi][ni] = __builtin_amdgcn_mfma_f32_16x16x32_bf16(
                a[mi], b[ni], acc[mi][ni], 0, 0, 0);
            acc[mi][ni] = __builtin_amdgcn_mfma_f32_16x16x32_bf16(
                a[mi], bl[ni], acc[mi][ni], 0, 0, 0);
            acc[mi][ni] = __builtin_amdgcn_mfma_f32_16x16x32_bf16(
                al[mi], b[ni], acc[mi][ni], 0, 0, 0);
          }
      } else {
#pragma unroll
        for (int mi = 0; mi < 4; ++mi)
#pragma unroll
          for (int ni = 0; ni < 4; ++ni)
            acc[mi][ni] = __builtin_amdgcn_mfma_f32_16x16x32_bf16(
                a[mi], b[ni], acc[mi][ni], 0, 0, 0);
      }
    }
    __syncthreads();
  }

#pragma unroll
  for (int mi = 0; mi < 4; ++mi)
#pragma unroll
    for (int ni = 0; ni < 4; ++ni)
#pragma unroll
      for (int r = 0; r < 4; ++r) {
        const int row = out_row0 + m0 + wm + mi * 16 + quad * 4 + r;
        const int col = n0 + wn + ni * 16 + l15;
        const float v = acc[mi][ni][r];
        if (OUT_MODE == 0) {
          ((float*)C0)[(size_t)row * ldc + col] = v;
        } else if (OUT_MODE == 1) {
          ((short*)C0)[(size_t)row * ldc + col] = f2bf(v);
        } else {
          const short h = f2bf(v);
          ((short*)C0)[(size_t)row * ldc + col] = h;
          ((short*)C1)[(size_t)row * ldc + col] = f2bf(v - bf2f(h));
        }
      }
}

// ---------------------------------------------------------------------------
// elementwise split: x -> hi bf16 + lo bf16 (x ~= hi + lo). One float4/thread.
// ---------------------------------------------------------------------------
__global__ __launch_bounds__(256)
void split_pair(const float* __restrict__ in, short* __restrict__ hi,
                short* __restrict__ lo) {
  const int idx = blockIdx.x * 256 + threadIdx.x;
  const float4 v = ((const float4*)in)[idx];
  short h[4], l[4];
  const float f[4] = {v.x, v.y, v.z, v.w};
#pragma unroll
  for (int i = 0; i < 4; ++i) {
    h[i] = f2bf(f[i]);
    l[i] = f2bf(f[i] - bf2f(h[i]));
  }
  ((short4*)hi)[idx] = make_short4(h[0], h[1], h[2], h[3]);
  ((short4*)lo)[idx] = make_short4(l[0], l[1], l[2], l[3]);
}

// ---------------------------------------------------------------------------
// transpose + bf16 convert: in R x C fp32 -> hi (C x R bf16), optional lo.
// ---------------------------------------------------------------------------
__global__ __launch_bounds__(256)
void transpose_split(const float* __restrict__ in, short* __restrict__ hi,
                     short* __restrict__ lo, int R, int C) {
  __shared__ short Th[64][72];
  __shared__ short Tl[64][72];
  const int tid = threadIdx.x;
  const int r0 = blockIdx.x * 64, c0 = blockIdx.y * 64;
#pragma unroll
  for (int i = 0; i < 4; ++i) {
    const int rr = (tid >> 4) + i * 16;
    const int cc = (tid & 15) * 4;
    const float4 v = *(const float4*)&in[(size_t)(r0 + rr) * C + c0 + cc];
    const float f[4] = {v.x, v.y, v.z, v.w};
#pragma unroll
    for (int j = 0; j < 4; ++j) {
      const short h = f2bf(f[j]);
      Th[rr][cc + j] = h;
      if (lo) Tl[rr][cc + j] = f2bf(f[j] - bf2f(h));
    }
  }
  __syncthreads();
#pragma unroll
  for (int i = 0; i < 2; ++i) {
    const int idx = tid + i * 256;
    const int oc = idx >> 3;
    const int ch = (idx & 7) * 8;
    float4 u;
    short* t = (short*)&u;
#pragma unroll
    for (int j = 0; j < 8; ++j) t[j] = Th[ch + j][oc];
    *(float4*)&hi[(size_t)(c0 + oc) * R + r0 + ch] = u;
    if (lo) {
#pragma unroll
      for (int j = 0; j < 8; ++j) t[j] = Tl[ch + j][oc];
      *(float4*)&lo[(size_t)(c0 + oc) * R + r0 + ch] = u;
    }
  }
}

// ---------------------------------------------------------------------------
// Row softmax, in place: S (band x 4096 fp32, band-local) -> P bf16 written
// over the same buffer (row li at (short*)S + li*8192, i.e. lda 8192 shorts).
// Zero-pads to the PV m-tile k-extent ((gi>>7)+1)*128. One block per row.
// ---------------------------------------------------------------------------
__global__ __launch_bounds__(256)
void softmax_inplace(float* __restrict__ S, int row0) {
  const int li = blockIdx.x;
  const int gi = row0 + li;
  const int valid = gi + 1;
  const int padded = ((gi >> 7) + 1) << 7;
  float* srow = S + (size_t)li * N_SEQ;
  short* prow = (short*)srow;
  const int tid = threadIdx.x;
  const int w = tid >> 6, lane = tid & 63;
  __shared__ float wred[4];
  __shared__ float sm, sil;

  float m = -1e30f;
  for (int j = tid; j < valid; j += 256) m = fmaxf(m, srow[j]);
#pragma unroll
  for (int off = 32; off > 0; off >>= 1) m = fmaxf(m, __shfl_down(m, off));
  if (lane == 0) wred[w] = m;
  __syncthreads();
  if (tid == 0) sm = fmaxf(fmaxf(wred[0], wred[1]), fmaxf(wred[2], wred[3]));
  __syncthreads();
  m = sm;

  float l = 0.f;
  for (int j = tid; j < valid; j += 256) l += __expf(srow[j] - m);
#pragma unroll
  for (int off = 32; off > 0; off >>= 1) l += __shfl_down(l, off);
  if (lane == 0) wred[w] = l;
  __syncthreads();
  if (tid == 0) sil = 1.f / (wred[0] + wred[1] + wred[2] + wred[3]);
  __syncthreads();
  const float il = sil;

  // register-stage exp values, then overwrite (bf16 aliases fp32 storage)
  float vals[16];
  int c = 0;
  for (int j = tid; j < padded; j += 256)
    vals[c++] = (j < valid) ? __expf(srow[j] - m) * il : 0.f;
  __syncthreads();
  c = 0;
  for (int j = tid; j < padded; j += 256) prow[j] = f2bf(vals[c++]);
}

// ---------------------------------------------------------------------------
extern "C" void kernel_launch(void* const* d_in, const int* in_sizes, int n_in,
                              void* d_out, int out_size, void* d_ws,
                              size_t ws_size, hipStream_t stream) {
  (void)in_sizes; (void)n_in; (void)out_size;
  const float* x   = (const float*)d_in[0];
  const float* wqk = (const float*)d_in[1];
  const float* wov = (const float*)d_in[2];
  float* out = (float*)d_out;

  const size_t MB = 1ull << 20;
  char* p = (char*)d_ws;
  short* xh    = (short*)(p);             // 8 MB  4096x1024
  short* xl    = (short*)(p + 8 * MB);    // 8 MB
  short* xbT   = (short*)(p + 16 * MB);   // 8 MB  1024x4096 (hi)
  short* wqkTh = (short*)(p + 24 * MB);   // 2 MB  1024x1024
  short* wqkTl = (short*)(p + 26 * MB);   // 2 MB
  short* wovT  = (short*)(p + 28 * MB);   // 2 MB
  short* ob    = (short*)(p + 30 * MB);   // 8 MB  4096x1024 bf16
  char* dyn = p + 38 * MB;
  // adaptive band: qh/ql (band*2KB each) + S (band*16KB)
  int band = 4096;
  while (band > 128 && 38 * MB + (size_t)band * 20 * 1024 > ws_size) band >>= 1;
  short* qh = (short*)dyn;
  short* ql = (short*)(dyn + (size_t)band * 2048);
  float* S  = (float*)(dyn + (size_t)band * 4096);

  // prep: splits and transposes
  split_pair<<<4096, 256, 0, stream>>>(x, xh, xl);
  transpose_split<<<dim3(16, 16), 256, 0, stream>>>(wqk, wqkTh, wqkTl, 1024, 1024);
  transpose_split<<<dim3(16, 16), 256, 0, stream>>>(wov, wovT, nullptr, 1024, 1024);
  transpose_split<<<dim3(64, 16), 256, 0, stream>>>(x, xbT, nullptr, 4096, 1024);

  const int nrt = band / 128;
  for (int row0 = 0; row0 < N_SEQ; row0 += band) {
    const int rt0 = row0 / 128;
    // q[band] = x[band] @ wqk  (split-bf16, fp32-accurate, out split hi/lo)
    mfma_nt<true, 2, false><<<dim3(8, nrt), 256, 0, stream>>>(
        xh + (size_t)row0 * 1024, xl + (size_t)row0 * 1024, 1024,
        wqkTh, wqkTl, 1024, qh, ql, 1024, 0, 0, 1024, 0);
    // S = q[band] @ x^T, causal tiles only (fp32 out)
    const int nblk = nrt * rt0 + nrt * (nrt + 1) / 2;
    mfma_nt<true, 0, true><<<nblk, 256, 0, stream>>>(
        qh, ql, 1024, xh, xl, 1024, S, nullptr, N_SEQ, 0, rt0, 1024, 0);
    // softmax rows -> P bf16 in place
    softmax_inplace<<<band, 256, 0, stream>>>(S, row0);
    // o[band] = P @ x  (bf16; B = x^T; K varies per m-tile: (rt0+mt+1)*128)
    mfma_nt<false, 1, false><<<dim3(8, nrt), 256, 0, stream>>>(
        (const short*)S, nullptr, 8192, xbT, nullptr, N_SEQ,
        ob, nullptr, 1024, row0, rt0, 128, 128);
  }

  // out = o @ wov (bf16 MFMA, fp32 out)
  mfma_nt<false, 0, false><<<dim3(8, 32), 256, 0, stream>>>(
      ob, nullptr, 1024, wovT, nullptr, 1024,
      out, nullptr, 1024, 0, 0, 1024, 0);
}

// Round 4
// 282.684 us; speedup vs baseline: 11.5837x; 1.1433x over previous
//
#include <hip/hip_runtime.h>
#include <hip/hip_bf16.h>
#include <math.h>

#define N_SEQ 4096
#define D_MODEL 1024

typedef __attribute__((ext_vector_type(8))) short short8;
typedef __attribute__((ext_vector_type(4))) float f32x4;

__device__ __forceinline__ short f2bf(float f) {
  __hip_bfloat16 h = __float2bfloat16(f);
  return *reinterpret_cast<short*>(&h);
}
__device__ __forceinline__ float bf2f(short h) {
  return __uint_as_float(((unsigned)(unsigned short)h) << 16);
}

// async global->LDS, 16B per lane. LDS dest must be wave-uniform base + lane*16.
__device__ __forceinline__ void gload16(const short* g, short* l) {
  __builtin_amdgcn_global_load_lds(
      (const __attribute__((address_space(1))) void*)g,
      (__attribute__((address_space(3))) void*)l, 16, 0, 0);
}

// ---------------------------------------------------------------------------
// XOR-swizzled staging: tile of ROWS x 64 shorts in LDS. Slot s (16B chunks):
// r = s>>3, c8 = (s&7) ^ (r&7)  -> fragment reads hit all 32 banks (2-way,
// free) instead of the 16-way conflict of the linear layout.
// HL: row = [hi 32 shorts | lo 32 shorts], K-step 32; else plain 64, K-step 64.
// ---------------------------------------------------------------------------
template <int ROWS, bool HL>
__device__ __forceinline__ void stage_sw(const short* __restrict__ hi,
                                         const short* __restrict__ lo, int ld,
                                         int r0, int k0, short* dst, int tid) {
#pragma unroll
  for (int i = 0; i < ROWS * 8 / 256; ++i) {
    const int s = i * 256 + tid;
    const int r = s >> 3;
    const int c8 = (s & 7) ^ (r & 7);
    const short* src;
    int col;
    if (HL) {
      src = (c8 < 4) ? hi : lo;
      col = (c8 & 3) * 8;
    } else {
      src = hi;
      col = c8 * 8;
    }
    gload16(&src[(size_t)(r0 + r) * ld + k0 + col], &dst[s * 8]);
  }
}

// ---------------------------------------------------------------------------
// bf16 MFMA GEMM (NT), 128 x BN tile, 256 thr = 4 waves.
//  BN=128: waves 2x2, each 64x64 (MI=4,NI=4). BN=64: waves 4x1, 32x64 (MI=2).
// HL: 3-product split-bf16 (fp32-grade): Ah*Bh + Ah*Bl + Al*Bh.
// OUT_MODE: 0 fp32, 1 bf16, 2 bf16 hi+lo split.
// MODE: 0 rect (y=mt,x=nt) | 1 causal flat (nt<=rt0+mt) | 2 PV flat
//       (nt=f&15, mt=31-(f>>4): longest-K blocks dispatch first, XCD-pinned nt).
// K = k_base + k_per_mt*(rt0+mt).
// ---------------------------------------------------------------------------
template <bool HL, int OUT_MODE, int MODE, int BN, int MINW>
__global__ __launch_bounds__(256, MINW)
void mfma_nt(const short* __restrict__ Ah, const short* __restrict__ Al,
             int lda, const short* __restrict__ Bh,
             const short* __restrict__ Bl, int ldb, void* __restrict__ C0,
             void* __restrict__ C1, int ldc, int out_row0, int rt0,
             int k_base, int k_per_mt) {
  constexpr int KSTEP = HL ? 32 : 64;
  constexpr int MI = (BN == 128) ? 4 : 2;
  constexpr int NI = 4;
  __shared__ short sA[128 * 64];
  __shared__ short sB[BN * 64];

  int mt, nt;
  if (MODE == 1) {
    int f = blockIdx.x, lrt = 0;
    for (;;) {
      const int cnt = rt0 + lrt + 1;
      if (f < cnt) break;
      f -= cnt;
      ++lrt;
    }
    mt = lrt;
    nt = f;
  } else if (MODE == 2) {
    nt = blockIdx.x & 15;
    mt = 31 - (blockIdx.x >> 4);
  } else {
    mt = blockIdx.y;
    nt = blockIdx.x;
  }
  const int m0 = mt * 128, n0 = nt * BN;
  const int K = k_base + k_per_mt * (rt0 + mt);

  const int tid = threadIdx.x;
  const int w = tid >> 6, lane = tid & 63;
  const int quad = lane >> 4, l15 = lane & 15;
  const int wm = (BN == 128) ? (w >> 1) * 64 : w * 32;
  const int wn = (BN == 128) ? (w & 1) * 64 : 0;

  f32x4 acc[MI][NI];
#pragma unroll
  for (int mi = 0; mi < MI; ++mi)
#pragma unroll
    for (int ni = 0; ni < NI; ++ni)
#pragma unroll
      for (int r = 0; r < 4; ++r) acc[mi][ni][r] = 0.f;

  const int nk = K / KSTEP;
  for (int kt = 0; kt < nk; ++kt) {
    const int k0 = kt * KSTEP;
    stage_sw<128, HL>(Ah, Al, lda, m0, k0, sA, tid);
    stage_sw<BN, HL>(Bh, Bl, ldb, n0, k0, sB, tid);
    __syncthreads();
    if (HL) {
      short8 a[MI], am[MI], b[NI], bm[NI];
#pragma unroll
      for (int mi = 0; mi < MI; ++mi) {
        const int rr = wm + mi * 16 + l15;
        a[mi] = *(const short8*)&sA[rr * 64 + ((quad ^ (rr & 7)) << 3)];
        am[mi] = *(const short8*)&sA[rr * 64 + (((quad + 4) ^ (rr & 7)) << 3)];
      }
#pragma unroll
      for (int ni = 0; ni < NI; ++ni) {
        const int rr = wn + ni * 16 + l15;
        b[ni] = *(const short8*)&sB[rr * 64 + ((quad ^ (rr & 7)) << 3)];
        bm[ni] = *(const short8*)&sB[rr * 64 + (((quad + 4) ^ (rr & 7)) << 3)];
      }
#pragma unroll
      for (int mi = 0; mi < MI; ++mi)
#pragma unroll
        for (int ni = 0; ni < NI; ++ni) {
          acc[mi][ni] = __builtin_amdgcn_mfma_f32_16x16x32_bf16(
              a[mi], b[ni], acc[mi][ni], 0, 0, 0);
          acc[mi][ni] = __builtin_amdgcn_mfma_f32_16x16x32_bf16(
              a[mi], bm[ni], acc[mi][ni], 0, 0, 0);
          acc[mi][ni] = __builtin_amdgcn_mfma_f32_16x16x32_bf16(
              am[mi], b[ni], acc[mi][ni], 0, 0, 0);
        }
    } else {
#pragma unroll
      for (int s = 0; s < 2; ++s) {
        short8 a[MI], b[NI];
#pragma unroll
        for (int mi = 0; mi < MI; ++mi) {
          const int rr = wm + mi * 16 + l15;
          a[mi] = *(const short8*)&sA[rr * 64 + (((s * 4 + quad) ^ (rr & 7)) << 3)];
        }
#pragma unroll
        for (int ni = 0; ni < NI; ++ni) {
          const int rr = wn + ni * 16 + l15;
          b[ni] = *(const short8*)&sB[rr * 64 + (((s * 4 + quad) ^ (rr & 7)) << 3)];
        }
#pragma unroll
        for (int mi = 0; mi < MI; ++mi)
#pragma unroll
          for (int ni = 0; ni < NI; ++ni)
            acc[mi][ni] = __builtin_amdgcn_mfma_f32_16x16x32_bf16(
                a[mi], b[ni], acc[mi][ni], 0, 0, 0);
      }
    }
    __syncthreads();
  }

#pragma unroll
  for (int mi = 0; mi < MI; ++mi)
#pragma unroll
    for (int ni = 0; ni < NI; ++ni)
#pragma unroll
      for (int r = 0; r < 4; ++r) {
        const int row = out_row0 + m0 + wm + mi * 16 + quad * 4 + r;
        const int col = n0 + wn + ni * 16 + l15;
        const float v = acc[mi][ni][r];
        if (OUT_MODE == 0) {
          ((float*)C0)[(size_t)row * ldc + col] = v;
        } else if (OUT_MODE == 1) {
          ((short*)C0)[(size_t)row * ldc + col] = f2bf(v);
        } else {
          const short h = f2bf(v);
          ((short*)C0)[(size_t)row * ldc + col] = h;
          ((short*)C1)[(size_t)row * ldc + col] = f2bf(v - bf2f(h));
        }
      }
}

// ---------------------------------------------------------------------------
// fused x prep: x (4096x1024 f32) -> xh, xl (row-major bf16) + xbT (1024x4096
// bf16 transpose of hi). One read of x.
// ---------------------------------------------------------------------------
__global__ __launch_bounds__(256)
void split_x(const float* __restrict__ in, short* __restrict__ hi,
             short* __restrict__ lo, short* __restrict__ hiT) {
  __shared__ short Th[64][72];
  const int tid = threadIdx.x;
  const int r0 = blockIdx.x * 64, c0 = blockIdx.y * 64;
#pragma unroll
  for (int i = 0; i < 4; ++i) {
    const int rr = (tid >> 4) + i * 16;
    const int cc = (tid & 15) * 4;
    const float4 v = *(const float4*)&in[(size_t)(r0 + rr) * D_MODEL + c0 + cc];
    const float f[4] = {v.x, v.y, v.z, v.w};
    short h[4], l[4];
#pragma unroll
    for (int j = 0; j < 4; ++j) {
      h[j] = f2bf(f[j]);
      l[j] = f2bf(f[j] - bf2f(h[j]));
      Th[rr][cc + j] = h[j];
    }
    *(short4*)&hi[(size_t)(r0 + rr) * D_MODEL + c0 + cc] =
        make_short4(h[0], h[1], h[2], h[3]);
    *(short4*)&lo[(size_t)(r0 + rr) * D_MODEL + c0 + cc] =
        make_short4(l[0], l[1], l[2], l[3]);
  }
  __syncthreads();
#pragma unroll
  for (int i = 0; i < 2; ++i) {
    const int idx = tid + i * 256;
    const int oc = idx >> 3;
    const int ch = (idx & 7) * 8;
    float4 u;
    short* t = (short*)&u;
#pragma unroll
    for (int j = 0; j < 8; ++j) t[j] = Th[ch + j][oc];
    *(float4*)&hiT[(size_t)(c0 + oc) * N_SEQ + r0 + ch] = u;
  }
}

// ---------------------------------------------------------------------------
// transpose + bf16 split: in R x C fp32 -> hi (C x R bf16), optional lo.
// ---------------------------------------------------------------------------
__global__ __launch_bounds__(256)
void transpose_split(const float* __restrict__ in, short* __restrict__ hi,
                     short* __restrict__ lo, int R, int C) {
  __shared__ short Th[64][72];
  __shared__ short Tl[64][72];
  const int tid = threadIdx.x;
  const int r0 = blockIdx.x * 64, c0 = blockIdx.y * 64;
#pragma unroll
  for (int i = 0; i < 4; ++i) {
    const int rr = (tid >> 4) + i * 16;
    const int cc = (tid & 15) * 4;
    const float4 v = *(const float4*)&in[(size_t)(r0 + rr) * C + c0 + cc];
    const float f[4] = {v.x, v.y, v.z, v.w};
#pragma unroll
    for (int j = 0; j < 4; ++j) {
      const short h = f2bf(f[j]);
      Th[rr][cc + j] = h;
      if (lo) Tl[rr][cc + j] = f2bf(f[j] - bf2f(h));
    }
  }
  __syncthreads();
#pragma unroll
  for (int i = 0; i < 2; ++i) {
    const int idx = tid + i * 256;
    const int oc = idx >> 3;
    const int ch = (idx & 7) * 8;
    float4 u;
    short* t = (short*)&u;
#pragma unroll
    for (int j = 0; j < 8; ++j) t[j] = Th[ch + j][oc];
    *(float4*)&hi[(size_t)(c0 + oc) * R + r0 + ch] = u;
    if (lo) {
#pragma unroll
      for (int j = 0; j < 8; ++j) t[j] = Tl[ch + j][oc];
      *(float4*)&lo[(size_t)(c0 + oc) * R + r0 + ch] = u;
    }
  }
}

// ---------------------------------------------------------------------------
// Row softmax, single pass, in place: S row (fp32) read once into registers,
// P bf16 written over the same storage. Pads row gi to ((gi>>7)+1)*128.
// ---------------------------------------------------------------------------
__global__ __launch_bounds__(256)
void softmax_inplace(float* __restrict__ S, int row0) {
  const int li = blockIdx.x;
  const int gi = row0 + li;
  const int valid = gi + 1;
  const int padded = ((gi >> 7) + 1) << 7;
  const int nf4 = padded >> 2;
  float* srow = S + (size_t)li * N_SEQ;
  short* prow = (short*)srow;
  const int tid = threadIdx.x;
  const int w = tid >> 6, lane = tid & 63;
  __shared__ float wred[4];
  __shared__ float sm, sil;

  float4 v[4];
  float m = -1e30f;
#pragma unroll
  for (int k = 0; k < 4; ++k) {
    const int j = tid + k * 256;
    if (j < nf4) {
      v[k] = ((const float4*)srow)[j];
      float* f = (float*)&v[k];
#pragma unroll
      for (int e = 0; e < 4; ++e)
        if (4 * j + e < valid) m = fmaxf(m, f[e]);
    }
  }
#pragma unroll
  for (int off = 32; off > 0; off >>= 1) m = fmaxf(m, __shfl_down(m, off));
  if (lane == 0) wred[w] = m;
  __syncthreads();
  if (tid == 0) sm = fmaxf(fmaxf(wred[0], wred[1]), fmaxf(wred[2], wred[3]));
  __syncthreads();
  m = sm;

  float l = 0.f;
#pragma unroll
  for (int k = 0; k < 4; ++k) {
    const int j = tid + k * 256;
    if (j < nf4) {
      float* f = (float*)&v[k];
#pragma unroll
      for (int e = 0; e < 4; ++e) {
        const float p = (4 * j + e < valid) ? __expf(f[e] - m) : 0.f;
        f[e] = p;
        l += p;
      }
    }
  }
#pragma unroll
  for (int off = 32; off > 0; off >>= 1) l += __shfl_down(l, off);
  if (lane == 0) wred[w] = l;
  __syncthreads();
  if (tid == 0) sil = 1.f / (wred[0] + wred[1] + wred[2] + wred[3]);
  __syncthreads();
  const float il = sil;

#pragma unroll
  for (int k = 0; k < 4; ++k) {
    const int j = tid + k * 256;
    if (j < nf4) {
      const float* f = (const float*)&v[k];
      *(short4*)&prow[4 * j] = make_short4(f2bf(f[0] * il), f2bf(f[1] * il),
                                           f2bf(f[2] * il), f2bf(f[3] * il));
    }
  }
}

// ---------------------------------------------------------------------------
extern "C" void kernel_launch(void* const* d_in, const int* in_sizes, int n_in,
                              void* d_out, int out_size, void* d_ws,
                              size_t ws_size, hipStream_t stream) {
  (void)in_sizes; (void)n_in; (void)out_size; (void)ws_size;
  const float* x   = (const float*)d_in[0];
  const float* wqk = (const float*)d_in[1];
  const float* wov = (const float*)d_in[2];
  float* out = (float*)d_out;

  const size_t MB = 1ull << 20;
  char* p = (char*)d_ws;
  short* xh    = (short*)(p);             //  8 MB 4096x1024 bf16 hi
  short* xl    = (short*)(p + 8 * MB);    //  8 MB           bf16 lo
  short* xbT   = (short*)(p + 16 * MB);   //  8 MB 1024x4096 bf16 hi^T
  short* wqkTh = (short*)(p + 24 * MB);   //  2 MB
  short* wqkTl = (short*)(p + 26 * MB);   //  2 MB
  short* wovT  = (short*)(p + 28 * MB);   //  2 MB
  short* ob    = (short*)(p + 30 * MB);   //  8 MB 4096x1024 bf16
  short* qh    = (short*)(p + 38 * MB);   //  8 MB
  short* ql    = (short*)(p + 46 * MB);   //  8 MB
  float* S     = (float*)(p + 54 * MB);   // 64 MB 4096x4096 fp32 (P aliases)
                                          // total 118 MB

  split_x<<<dim3(64, 16), 256, 0, stream>>>(x, xh, xl, xbT);
  transpose_split<<<dim3(16, 16), 256, 0, stream>>>(wqk, wqkTh, wqkTl, 1024, 1024);
  transpose_split<<<dim3(16, 16), 256, 0, stream>>>(wov, wovT, nullptr, 1024, 1024);

  // q = x @ wqk  (split-bf16 3-product, out split hi/lo)
  mfma_nt<true, 2, 0, 128, 2><<<dim3(8, 32), 256, 0, stream>>>(
      xh, xl, 1024, wqkTh, wqkTl, 1024, qh, ql, 1024, 0, 0, D_MODEL, 0);
  // S = q @ x^T, causal tiles only (fp32)
  mfma_nt<true, 0, 1, 128, 2><<<528, 256, 0, stream>>>(
      qh, ql, 1024, xh, xl, 1024, S, nullptr, N_SEQ, 0, 0, D_MODEL, 0);
  // softmax rows -> P bf16 in place
  softmax_inplace<<<N_SEQ, 256, 0, stream>>>(S, 0);
  // o = P @ x  (bf16; 128x64 tiles, longest-K first, XCD-pinned nt)
  mfma_nt<false, 1, 2, 64, 4><<<512, 256, 0, stream>>>(
      (const short*)S, nullptr, 8192, xbT, nullptr, N_SEQ,
      ob, nullptr, 1024, 0, 0, 128, 128);
  // out = o @ wov (bf16, fp32 out)
  mfma_nt<false, 0, 0, 128, 3><<<dim3(8, 32), 256, 0, stream>>>(
      ob, nullptr, 1024, wovT, nullptr, 1024, out, nullptr, 1024, 0, 0,
      D_MODEL, 0);
}